// Round 8
// baseline (116.337 us; speedup 1.0000x reference)
//
#include <hip/hip_runtime.h>
#include <hip/hip_bf16.h>

// BiClassifier B=4 N=128 D=768 HID=1024 OUT=2
// k0 hid_init: hid[r][c] = (r<512 ? b1[c] : 0)                     [R5-proven]
// k1 prepack:  Abig[1024][2304] bf16 = [hi|lo|hi], Wbig = [hi|hi|lo] [R6-proven]
// k2 gemm_mfma v5: hid += Abig @ Wbig[sel].T
//     split-K x6 (1536 blocks = 6/CU), BK=64, single-buffered LDS (16KB),
//     gl_lds16 staging + (r&7) XOR swizzle, atomicAdd epilogue.
// k3 out_init: out[p][:] = bo                                      [R5-proven]
// k4 pair: 16x16 pair tile x h-range 256, atomicAdd partials       [R7-proven]

typedef __attribute__((ext_vector_type(8))) short s16x8;
typedef __attribute__((ext_vector_type(4))) float f32x4;

#define KP 2304
#define BK 64
#define KSPLIT 6
#define KRANGE 384           // KP / KSPLIT
#define NSTEPK (KRANGE / BK) // 6

__device__ __forceinline__ void gl_lds16(const void* g, void* l) {
    __builtin_amdgcn_global_load_lds(
        (const __attribute__((address_space(1))) unsigned int*)g,
        (__attribute__((address_space(3))) unsigned int*)l, 16, 0, 0);
}

__global__ __launch_bounds__(256) void hid_init(
    const float* __restrict__ b1, float* __restrict__ hid)
{
    const int g   = blockIdx.x * 256 + threadIdx.x;   // 262144 float4s
    const int row = g >> 8;
    const int c4  = (g & 255) << 2;
    float4 v = make_float4(0.f, 0.f, 0.f, 0.f);
    if (row < 512) v = *(const float4*)&b1[c4];
    *(float4*)&hid[(size_t)row * 1024 + c4] = v;
}

__global__ __launch_bounds__(256) void prepack(
    const float* __restrict__ in1, const float* __restrict__ in2,
    const float* __restrict__ W1, const float* __restrict__ W2,
    ushort* __restrict__ Abig, ushort* __restrict__ Wbig)
{
    const int gid = blockIdx.x * 256 + threadIdx.x;   // 589824 total
    const int src = gid / 196608;                     // 0:A 1:W1 2:W2
    const int rem = gid % 196608;
    const int row = rem / 192;
    const int k4  = (rem % 192) * 4;
    const float* sp;
    ushort* dst;
    if (src == 0) {
        sp  = (row < 512) ? in1 + (size_t)row * 768 + k4
                          : in2 + (size_t)(row - 512) * 768 + k4;
        dst = Abig + (size_t)row * KP + k4;
    } else {
        sp  = (src == 1 ? W1 : W2) + (size_t)row * 768 + k4;
        dst = Wbig + (size_t)(src - 1) * (1024 * KP) + (size_t)row * KP + k4;
    }
    const float4 x = *(const float4*)sp;
    const float xf[4] = {x.x, x.y, x.z, x.w};
    ushort h[4], l[4];
    #pragma unroll
    for (int i = 0; i < 4; ++i) {
        const float v = xf[i];
        __hip_bfloat16 bh = __float2bfloat16(v);
        const float fh = __bfloat162float(bh);
        __hip_bfloat16 bl = __float2bfloat16(v - fh);
        h[i] = *(ushort*)&bh;
        l[i] = *(ushort*)&bl;
    }
    const ushort4 H = make_ushort4(h[0], h[1], h[2], h[3]);
    const ushort4 L = make_ushort4(l[0], l[1], l[2], l[3]);
    if (src == 0) {   // A: [hi | lo | hi]
        *(ushort4*)(dst)        = H;
        *(ushort4*)(dst + 768)  = L;
        *(ushort4*)(dst + 1536) = H;
    } else {          // W: [hi | hi | lo]
        *(ushort4*)(dst)        = H;
        *(ushort4*)(dst + 768)  = H;
        *(ushort4*)(dst + 1536) = L;
    }
}

// 64x64 tile, 4 waves (2x2 of 32x32), split-K x6, single-buffered BK=64.
__global__ __launch_bounds__(256) void gemm_mfma(
    const ushort* __restrict__ Abig, const ushort* __restrict__ Wbig,
    float* __restrict__ hid)
{
    const int t    = threadIdx.x;
    const int lane = t & 63;
    const int w    = t >> 6;
    const int row0 = blockIdx.y * 64;
    const int col0 = blockIdx.x * 64;
    const int k0   = blockIdx.z * KRANGE;

    const char* __restrict__ A = (const char*)(Abig + (size_t)row0 * KP + k0);
    const char* __restrict__ W = (const char*)(Wbig
                                   + (row0 < 512 ? (size_t)0 : (size_t)1024 * KP)
                                   + (size_t)col0 * KP + k0);

    __shared__ ushort lds[2][4096];   // [A/W][8KB], single-buffered

    // staging: slot = q*256+t covers 16B chunk; row = slot>>3, chunk = (slot&7)^(row&7)
    int srow[2], cbyt[2];
    #pragma unroll
    for (int q = 0; q < 2; ++q) {
        const int slot = q * 256 + t;
        srow[q] = slot >> 3;
        cbyt[q] = ((slot & 7) ^ (srow[q] & 7)) << 4;
    }

    // fragment read offsets: phys_byte_in_row = logical ^ ((row&7)<<4)
    const int wr = w >> 1, wc = w & 1;
    const int l15 = lane & 15, kg = lane >> 4;
    int aoff[2][2], boff[2][2];   // [kk][frag]
    #pragma unroll
    for (int kk = 0; kk < 2; ++kk)
        #pragma unroll
        for (int f = 0; f < 2; ++f) {
            const int r = wr * 32 + f * 16 + l15;
            const int c = wc * 32 + f * 16 + l15;
            const int sw_ = kk * 64 + kg * 16;
            aoff[kk][f] = r * 128 + (sw_ ^ ((r & 7) << 4));
            boff[kk][f] = c * 128 + (sw_ ^ ((c & 7) << 4));
        }

    const f32x4 zero = {0.f, 0.f, 0.f, 0.f};
    f32x4 acc[2][2] = {{zero, zero}, {zero, zero}};

    for (int kt = 0; kt < NSTEPK; ++kt) {
        #pragma unroll
        for (int q = 0; q < 2; ++q) {
            const size_t off = (size_t)srow[q] * (KP * 2) + kt * (BK * 2) + cbyt[q];
            const int dst = (q * 256 + t) * 16;
            gl_lds16(A + off, (char*)&lds[0][0] + dst);
            gl_lds16(W + off, (char*)&lds[1][0] + dst);
        }
        __syncthreads();   // drains vmcnt -> staged data visible
        #pragma unroll
        for (int kk = 0; kk < 2; ++kk) {
            s16x8 af[2], bf_[2];
            #pragma unroll
            for (int f = 0; f < 2; ++f) {
                af[f]  = *(const s16x8*)((const char*)&lds[0][0] + aoff[kk][f]);
                bf_[f] = *(const s16x8*)((const char*)&lds[1][0] + boff[kk][f]);
            }
            #pragma unroll
            for (int fr = 0; fr < 2; ++fr)
                #pragma unroll
                for (int fc = 0; fc < 2; ++fc)
                    acc[fr][fc] = __builtin_amdgcn_mfma_f32_16x16x32_bf16(
                        af[fr], bf_[fc], acc[fr][fc], 0, 0, 0);
        }
        __syncthreads();   // protect LDS before next stage overwrites
    }

    // C/D layout: col = lane&15, row = (lane>>4)*4 + i
    #pragma unroll
    for (int fr = 0; fr < 2; ++fr)
        #pragma unroll
        for (int fc = 0; fc < 2; ++fc)
            #pragma unroll
            for (int i = 0; i < 4; ++i) {
                const int r = row0 + wr * 32 + fr * 16 + kg * 4 + i;
                const int c = col0 + wc * 32 + fc * 16 + l15;
                atomicAdd(&hid[(size_t)r * 1024 + c], acc[fr][fc][i]);
            }
}

__global__ __launch_bounds__(256) void out_init(
    const float* __restrict__ bo, float* __restrict__ out)
{
    const int g = blockIdx.x * 256 + threadIdx.x;   // 65536 pairs
    *(float2*)&out[(size_t)g * 2] = make_float2(bo[0], bo[1]);
}

// 16x16 pair tile x h-range 256. Grid (8,8,16): z = b*4 + h-split.
__global__ __launch_bounds__(256) void pair_kernel(
    const float* __restrict__ hid, const float* __restrict__ Wo,
    float* __restrict__ out)
{
    const int t  = threadIdx.x;
    const int b  = blockIdx.z >> 2;
    const int h0 = (blockIdx.z & 3) * 256;
    const int n0 = blockIdx.y * 16;
    const int m0 = blockIdx.x * 16;

    __shared__ float s1[16][260];
    __shared__ float s2[16][260];
    __shared__ float sw[2][256];

    const float* __restrict__ base1 = hid + ((size_t)(b * 128 + n0)) * 1024 + h0;
    const float* __restrict__ base2 = hid + ((size_t)(512 + b * 128 + m0)) * 1024 + h0;

    #pragma unroll
    for (int p = 0; p < 4; ++p) {
        const int slot = p * 256 + t;
        const int r  = slot >> 6;
        const int c  = (slot & 63) << 2;
        *(float4*)&s1[r][c] = *(const float4*)&base1[(size_t)r * 1024 + c];
        *(float4*)&s2[r][c] = *(const float4*)&base2[(size_t)r * 1024 + c];
    }
    if (t < 128) {
        const int o = t >> 6;
        const int c = (t & 63) << 2;
        *(float4*)&sw[o][c] = *(const float4*)&Wo[(size_t)o * 1024 + h0 + c];
    }
    __syncthreads();

    const int i = t >> 4, j = t & 15;
    const float* __restrict__ xrow = &s1[i][0];
    const float* __restrict__ yrow = &s2[j][0];
    float acc0 = 0.f, acc1 = 0.f;

    #pragma unroll 8
    for (int c4 = 0; c4 < 64; ++c4) {
        const float4 x  = *(const float4*)&xrow[c4 * 4];
        const float4 y  = *(const float4*)&yrow[c4 * 4];
        const float4 uu = *(const float4*)&sw[0][c4 * 4];
        const float4 vv = *(const float4*)&sw[1][c4 * 4];
        float r;
        r = fmaxf(x.x + y.x, 0.f); acc0 = fmaf(r, uu.x, acc0); acc1 = fmaf(r, vv.x, acc1);
        r = fmaxf(x.y + y.y, 0.f); acc0 = fmaf(r, uu.y, acc0); acc1 = fmaf(r, vv.y, acc1);
        r = fmaxf(x.z + y.z, 0.f); acc0 = fmaf(r, uu.z, acc0); acc1 = fmaf(r, vv.z, acc1);
        r = fmaxf(x.w + y.w, 0.f); acc0 = fmaf(r, uu.w, acc0); acc1 = fmaf(r, vv.w, acc1);
    }

    const size_t P = (((size_t)b * 128 + n0 + i) * 128 + (m0 + j)) * 2;
    atomicAdd(&out[P],     acc0);
    atomicAdd(&out[P + 1], acc1);
}

extern "C" void kernel_launch(void* const* d_in, const int* in_sizes, int n_in,
                              void* d_out, int out_size, void* d_ws, size_t ws_size,
                              hipStream_t stream) {
    (void)in_sizes; (void)n_in; (void)out_size; (void)ws_size;
    const float* input1 = (const float*)d_in[0];
    const float* input2 = (const float*)d_in[1];
    const float* W1     = (const float*)d_in[2];
    const float* b1     = (const float*)d_in[3];
    const float* W2     = (const float*)d_in[4];
    const float* Wo     = (const float*)d_in[5];
    const float* bo     = (const float*)d_in[6];
    float* out = (float*)d_out;

    ushort* Abig = (ushort*)d_ws;                           // 4.72 MB
    ushort* Wbig = Abig + (size_t)1024 * KP;                // 9.44 MB
    float*  hid  = (float*)(Wbig + (size_t)2 * 1024 * KP);  // 4 MB

    hid_init<<<1024, 256, 0, stream>>>(b1, hid);
    prepack<<<2304, 256, 0, stream>>>(input1, input2, W1, W2, Abig, Wbig);
    gemm_mfma<<<dim3(16, 16, KSPLIT), 256, 0, stream>>>(Abig, Wbig, hid);
    out_init<<<256, 256, 0, stream>>>(bo, out);
    pair_kernel<<<dim3(8, 8, 16), 256, 0, stream>>>(hid, Wo, out);
}

// Round 10
// 95.110 us; speedup vs baseline: 1.2232x; 1.2232x over previous
//
#include <hip/hip_runtime.h>
#include <hip/hip_bf16.h>

// BiClassifier B=4 N=128 D=768 HID=1024 OUT=2
// R9 (resubmit — R9 bench never ran: acquisition timeout):
// single-term bf16 GEMM (K'=768, no hi/lo split) — error budget analysis
// says absmax ~0.01 < 0.0253 threshold. Structure identical to R7 (best measured).
// k1 prepack:  Abig[1024][768] bf16, Wbig[2][1024][768] bf16 (plain converts)
// k2 gemm_mfma: hid = Abig @ Wbig[sel].T + b1, in-block split-K x2, LDS reduce,
//               plain stores [R6/R7-proven structure, K constants /3]
// k3 out_init: out[p][:] = bo                                   [R5-proven]
// k4 pair: 16x16 pair tile x h-range 256, atomicAdd partials    [R7-proven]

typedef __attribute__((ext_vector_type(8))) short s16x8;
typedef __attribute__((ext_vector_type(4))) float f32x4;

#define KP 768
#define BK 64
#define KHALF 384
#define NSTEP (KHALF / BK)   // 6

__device__ __forceinline__ void gl_lds16(const void* g, void* l) {
    __builtin_amdgcn_global_load_lds(
        (const __attribute__((address_space(1))) unsigned int*)g,
        (__attribute__((address_space(3))) unsigned int*)l, 16, 0, 0);
}

__global__ __launch_bounds__(256) void prepack(
    const float* __restrict__ in1, const float* __restrict__ in2,
    const float* __restrict__ W1, const float* __restrict__ W2,
    ushort* __restrict__ Abig, ushort* __restrict__ Wbig)
{
    const int gid = blockIdx.x * 256 + threadIdx.x;   // 589824 total
    const int src = gid / 196608;                     // 0:A 1:W1 2:W2
    const int rem = gid % 196608;
    const int row = rem / 192;
    const int k4  = (rem % 192) * 4;
    const float* sp;
    ushort* dst;
    if (src == 0) {
        sp  = (row < 512) ? in1 + (size_t)row * 768 + k4
                          : in2 + (size_t)(row - 512) * 768 + k4;
        dst = Abig + (size_t)row * KP + k4;
    } else {
        sp  = (src == 1 ? W1 : W2) + (size_t)row * 768 + k4;
        dst = Wbig + (size_t)(src - 1) * (1024 * KP) + (size_t)row * KP + k4;
    }
    const float4 x = *(const float4*)sp;
    const float xf[4] = {x.x, x.y, x.z, x.w};
    ushort h[4];
    #pragma unroll
    for (int i = 0; i < 4; ++i) {
        __hip_bfloat16 bh = __float2bfloat16(xf[i]);
        h[i] = *(ushort*)&bh;
    }
    *(ushort4*)dst = make_ushort4(h[0], h[1], h[2], h[3]);
}

// 64x64 tile, 512 thr = 8 waves: w>>2 = K-half, w&3 = space wave (2x2 of 32x32).
// Double-buffered gl_lds16 staging (swizzle-inverse global src, linear LDS dest,
// XOR-swizzled reads). LDS cross-wave K-reduce epilogue, plain stores.
__global__ __launch_bounds__(512) void gemm_mfma(
    const ushort* __restrict__ Abig, const ushort* __restrict__ Wbig,
    const float* __restrict__ b1, float* __restrict__ hid)
{
    const int t    = threadIdx.x;
    const int lane = t & 63;
    const int w    = t >> 6;
    const int kh   = w >> 2;        // K-half 0/1
    const int ws   = w & 3;         // space wave
    const int row0 = blockIdx.y * 64;
    const int col0 = blockIdx.x * 64;

    const char* __restrict__ A = (const char*)(Abig + (size_t)row0 * KP);
    const char* __restrict__ W = (const char*)(Wbig
                                   + (row0 < 512 ? (size_t)0 : (size_t)1024 * KP)
                                   + (size_t)col0 * KP);

    __shared__ ushort lds[2][2][2][4096];   // [buf][kh][A/W][8KB] = 64KB

    const int srow = t >> 3;
    const int kbyt = (((t & 7) ^ (srow & 7)) << 4);
    const size_t rowoff = (size_t)srow * (KP * 2);

    const int wr = ws >> 1, wc = ws & 1;
    const int l15 = lane & 15, kg = lane >> 4;
    int aoff[2][2], boff[2][2];   // [kk][frag]
    #pragma unroll
    for (int kk = 0; kk < 2; ++kk)
        #pragma unroll
        for (int f = 0; f < 2; ++f) {
            const int r = wr * 32 + f * 16 + l15;
            const int c = wc * 32 + f * 16 + l15;
            const int sw_ = kk * 64 + kg * 16;
            aoff[kk][f] = r * 128 + (sw_ ^ ((r & 7) << 4));
            boff[kk][f] = c * 128 + (sw_ ^ ((c & 7) << 4));
        }

#define STAGE(buf, ktk) do {                                                   \
        const size_t kby = (size_t)(ktk) * (BK * 2);                           \
        _Pragma("unroll")                                                      \
        for (int p = 0; p < 4; ++p) {                                          \
            const char* src = (p & 1) ? W : A;                                 \
            const size_t off = rowoff + (size_t)(p >> 1) * (KHALF * 2)         \
                               + kby + kbyt;                                   \
            gl_lds16(src + off,                                                \
                     (char*)&lds[buf][p >> 1][p & 1][0] + t * 16);             \
        }                                                                      \
    } while (0)

    const f32x4 zero = {0.f, 0.f, 0.f, 0.f};
    f32x4 acc[2][2] = {{zero, zero}, {zero, zero}};

    STAGE(0, 0);
    int cur = 0;
    for (int kt = 0; kt < NSTEP; ++kt) {
        asm volatile("s_waitcnt vmcnt(0)" ::: "memory");
        __syncthreads();
        if (kt + 1 < NSTEP) STAGE(cur ^ 1, kt + 1);
        const char* __restrict__ ab = (const char*)&lds[cur][kh][0][0];
        const char* __restrict__ wb = (const char*)&lds[cur][kh][1][0];
        #pragma unroll
        for (int kk = 0; kk < 2; ++kk) {
            s16x8 af[2], bf_[2];
            #pragma unroll
            for (int f = 0; f < 2; ++f) {
                af[f]  = *(const s16x8*)(ab + aoff[kk][f]);
                bf_[f] = *(const s16x8*)(wb + boff[kk][f]);
            }
            #pragma unroll
            for (int fr = 0; fr < 2; ++fr)
                #pragma unroll
                for (int fc = 0; fc < 2; ++fc)
                    acc[fr][fc] = __builtin_amdgcn_mfma_f32_16x16x32_bf16(
                        af[fr], bf_[fc], acc[fr][fc], 0, 0, 0);
        }
        cur ^= 1;
    }
#undef STAGE

    __syncthreads();
    float* red = (float*)&lds[0][0][0][0];
    if (kh == 1) {
        #pragma unroll
        for (int fr = 0; fr < 2; ++fr)
            #pragma unroll
            for (int fc = 0; fc < 2; ++fc)
                *(f32x4*)&red[(((ws * 2 + fr) * 2 + fc) * 64 + lane) * 4] =
                    acc[fr][fc];
    }
    __syncthreads();
    if (kh == 0) {
        float bias[2] = {0.f, 0.f};
        if (row0 < 512) {
            bias[0] = b1[col0 + wc * 32 + l15];
            bias[1] = b1[col0 + wc * 32 + 16 + l15];
        }
        #pragma unroll
        for (int fr = 0; fr < 2; ++fr)
            #pragma unroll
            for (int fc = 0; fc < 2; ++fc) {
                const f32x4 o = *(const f32x4*)
                    &red[(((ws * 2 + fr) * 2 + fc) * 64 + lane) * 4];
                #pragma unroll
                for (int i = 0; i < 4; ++i) {
                    const int r = row0 + wr * 32 + fr * 16 + kg * 4 + i;
                    const int c = col0 + wc * 32 + fc * 16 + l15;
                    hid[(size_t)r * 1024 + c] = acc[fr][fc][i] + o[i] + bias[fc];
                }
            }
    }
}

__global__ __launch_bounds__(256) void out_init(
    const float* __restrict__ bo, float* __restrict__ out)
{
    const int g = blockIdx.x * 256 + threadIdx.x;   // 65536 pairs
    *(float2*)&out[(size_t)g * 2] = make_float2(bo[0], bo[1]);
}

// 16x16 pair tile x h-range 256. Grid (8,8,16): z = b*4 + h-split.
__global__ __launch_bounds__(256) void pair_kernel(
    const float* __restrict__ hid, const float* __restrict__ Wo,
    float* __restrict__ out)
{
    const int t  = threadIdx.x;
    const int b  = blockIdx.z >> 2;
    const int h0 = (blockIdx.z & 3) * 256;
    const int n0 = blockIdx.y * 16;
    const int m0 = blockIdx.x * 16;

    __shared__ float s1[16][260];
    __shared__ float s2[16][260];
    __shared__ float sw[2][256];

    const float* __restrict__ base1 = hid + ((size_t)(b * 128 + n0)) * 1024 + h0;
    const float* __restrict__ base2 = hid + ((size_t)(512 + b * 128 + m0)) * 1024 + h0;

    #pragma unroll
    for (int p = 0; p < 4; ++p) {
        const int slot = p * 256 + t;
        const int r  = slot >> 6;
        const int c  = (slot & 63) << 2;
        *(float4*)&s1[r][c] = *(const float4*)&base1[(size_t)r * 1024 + c];
        *(float4*)&s2[r][c] = *(const float4*)&base2[(size_t)r * 1024 + c];
    }
    if (t < 128) {
        const int o = t >> 6;
        const int c = (t & 63) << 2;
        *(float4*)&sw[o][c] = *(const float4*)&Wo[(size_t)o * 1024 + h0 + c];
    }
    __syncthreads();

    const int i = t >> 4, j = t & 15;
    const float* __restrict__ xrow = &s1[i][0];
    const float* __restrict__ yrow = &s2[j][0];
    float acc0 = 0.f, acc1 = 0.f;

    #pragma unroll 8
    for (int c4 = 0; c4 < 64; ++c4) {
        const float4 x  = *(const float4*)&xrow[c4 * 4];
        const float4 y  = *(const float4*)&yrow[c4 * 4];
        const float4 uu = *(const float4*)&sw[0][c4 * 4];
        const float4 vv = *(const float4*)&sw[1][c4 * 4];
        float r;
        r = fmaxf(x.x + y.x, 0.f); acc0 = fmaf(r, uu.x, acc0); acc1 = fmaf(r, vv.x, acc1);
        r = fmaxf(x.y + y.y, 0.f); acc0 = fmaf(r, uu.y, acc0); acc1 = fmaf(r, vv.y, acc1);
        r = fmaxf(x.z + y.z, 0.f); acc0 = fmaf(r, uu.z, acc0); acc1 = fmaf(r, vv.z, acc1);
        r = fmaxf(x.w + y.w, 0.f); acc0 = fmaf(r, uu.w, acc0); acc1 = fmaf(r, vv.w, acc1);
    }

    const size_t P = (((size_t)b * 128 + n0 + i) * 128 + (m0 + j)) * 2;
    atomicAdd(&out[P],     acc0);
    atomicAdd(&out[P + 1], acc1);
}

extern "C" void kernel_launch(void* const* d_in, const int* in_sizes, int n_in,
                              void* d_out, int out_size, void* d_ws, size_t ws_size,
                              hipStream_t stream) {
    (void)in_sizes; (void)n_in; (void)out_size; (void)ws_size;
    const float* input1 = (const float*)d_in[0];
    const float* input2 = (const float*)d_in[1];
    const float* W1     = (const float*)d_in[2];
    const float* b1     = (const float*)d_in[3];
    const float* W2     = (const float*)d_in[4];
    const float* Wo     = (const float*)d_in[5];
    const float* bo     = (const float*)d_in[6];
    float* out = (float*)d_out;

    ushort* Abig = (ushort*)d_ws;                           // 1.5 MB
    ushort* Wbig = Abig + (size_t)1024 * KP;                // 3 MB
    float*  hid  = (float*)(Wbig + (size_t)2 * 1024 * KP);  // 4 MB

    prepack<<<2304, 256, 0, stream>>>(input1, input2, W1, W2, Abig, Wbig);
    gemm_mfma<<<dim3(16, 16), 512, 0, stream>>>(Abig, Wbig, b1, hid);
    out_init<<<256, 256, 0, stream>>>(bo, out);
    pair_kernel<<<dim3(8, 8, 16), 256, 0, stream>>>(hid, Wo, out);
}